// Round 7
// baseline (105.303 us; speedup 1.0000x reference)
//
#include <hip/hip_runtime.h>
#include <hip/hip_bf16.h>

typedef unsigned short u16;
typedef __bf16 bf16x8 __attribute__((ext_vector_type(8)));
typedef float  f32x4  __attribute__((ext_vector_type(4)));

#define BB    4
#define SS    4096
#define DD    1024
#define EE    8
#define M_TOT (BB*SS)   /* 16384 */
#define N_TOT DD        /* 1024  */
#define K_TOT DD        /* 1024  */

#define BM 256
#define BN 128
#define BK 64
#define NT (K_TOT/BK)   /* 16 K-tiles */

#define GATE_BLOCKS 1024   /* 16 tokens per block, 4 per wave */

__device__ __forceinline__ u16 f2bf(float f) {
  unsigned u = __builtin_bit_cast(unsigned, f);
  u += 0x7fffu + ((u >> 16) & 1u);          // round-to-nearest-even
  return (u16)(u >> 16);
}

__device__ __forceinline__ void stage16(u16* lds, const u16* g) {
  __builtin_amdgcn_global_load_lds((const __attribute__((address_space(1))) void*)g,
                                   (__attribute__((address_space(3))) void*)lds,
                                   16, 0, 0);
}

// ---------------------------------------------------------------------------
// Kernel 1: gate (fp32, exact) + token f32->bf16 convert, plus weight convert.
// (unchanged — measured ~92% of achievable HBM BW)
// ---------------------------------------------------------------------------
__global__ __launch_bounds__(256) void gate_convert_kernel(
    const float* __restrict__ tokens, const float* __restrict__ gate_w,
    const float* __restrict__ w0,     const float* __restrict__ w1,
    u16* __restrict__ tok_bf, u16* __restrict__ w0_bf, u16* __restrict__ w1_bf,
    float* __restrict__ scales)
{
  const int bid = blockIdx.x;
  const int tid = threadIdx.x;

  if (bid < GATE_BLOCKS) {
    __shared__ float gwT[EE][DD];       // 32 KB, transposed gate weights
    #pragma unroll
    for (int r = 0; r < 4; ++r) {
      const int d = r * 256 + tid;      // coalesced: lanes 32B apart
      float4 a = *(const float4*)&gate_w[d * EE];
      float4 b = *(const float4*)&gate_w[d * EE + 4];
      gwT[0][d] = a.x; gwT[1][d] = a.y; gwT[2][d] = a.z; gwT[3][d] = a.w;
      gwT[4][d] = b.x; gwT[5][d] = b.y; gwT[6][d] = b.z; gwT[7][d] = b.w;
    }
    __syncthreads();

    const int lane = tid & 63, wid = tid >> 6;
    const int tbase = (bid * 4 + wid) * 4;          // 4 tokens per wave

    float lg[4][EE];
    #pragma unroll
    for (int t = 0; t < 4; ++t)
      #pragma unroll
      for (int e = 0; e < EE; ++e) lg[t][e] = 0.0f;

    #pragma unroll
    for (int c = 0; c < 4; ++c) {
      const int d = c * 256 + lane * 4;
      float4 gw[EE];
      #pragma unroll
      for (int e = 0; e < EE; ++e)
        gw[e] = *(const float4*)&gwT[e][d];         // ds_read_b128, lanes 16B apart
      #pragma unroll
      for (int t = 0; t < 4; ++t) {
        const size_t off = (size_t)(tbase + t) * DD + d;
        float4 v = *(const float4*)(tokens + off);
        *(ushort4*)(tok_bf + off) =
            make_ushort4(f2bf(v.x), f2bf(v.y), f2bf(v.z), f2bf(v.w));
        #pragma unroll
        for (int e = 0; e < EE; ++e)
          lg[t][e] = fmaf(v.w, gw[e].w, fmaf(v.z, gw[e].z,
                     fmaf(v.y, gw[e].y, fmaf(v.x, gw[e].x, lg[t][e]))));
      }
    }

    // Expert-splitting butterfly reduce, then shuffle softmax/top-2.
    const int b0 = lane & 1, b1 = (lane >> 1) & 1, b2 = (lane >> 2) & 1;
    const int E  = b0 * 4 + (lane & 2) + b2;

    #pragma unroll
    for (int t = 0; t < 4; ++t) {
      float n0[4], n1[2], rr;
      #pragma unroll
      for (int i = 0; i < 4; ++i) {
        float send = b0 ? lg[t][i] : lg[t][i + 4];
        float keep = b0 ? lg[t][i + 4] : lg[t][i];
        n0[i] = keep + __shfl_xor(send, 1, 64);
      }
      #pragma unroll
      for (int i = 0; i < 2; ++i) {
        float send = b1 ? n0[i] : n0[i + 2];
        float keep = b1 ? n0[i + 2] : n0[i];
        n1[i] = keep + __shfl_xor(send, 2, 64);
      }
      {
        float send = b2 ? n1[0] : n1[1];
        float keep = b2 ? n1[1] : n1[0];
        rr = keep + __shfl_xor(send, 4, 64);
      }
      rr += __shfl_xor(rr, 8, 64);
      rr += __shfl_xor(rr, 16, 64);
      rr += __shfl_xor(rr, 32, 64);

      float m = rr;
      m = fmaxf(m, __shfl_xor(m, 1, 64));
      m = fmaxf(m, __shfl_xor(m, 2, 64));
      m = fmaxf(m, __shfl_xor(m, 4, 64));
      float p = __expf(rr - m);
      float s = p;
      s += __shfl_xor(s, 1, 64);
      s += __shfl_xor(s, 2, 64);
      s += __shfl_xor(s, 4, 64);

      int cnt = 0;
      #pragma unroll
      for (int k = 1; k < 8; ++k) {
        float Lo = __shfl_xor(rr, k, 64);
        const int Eo = E ^ ((k & 1) * 4 + (k & 2) + ((k >> 2) & 1));
        cnt += (Lo > rr || (Lo == rr && Eo < E)) ? 1 : 0;
      }
      if (lane < 8) {
        const float w = p / s;
        if (E == 0) scales[(tbase + t) * 2 + 0] = (cnt == 0) ? w : 0.0f;
        if (E == 1) scales[(tbase + t) * 2 + 1] = (cnt == 1) ? w : 0.0f;
      }
    }
  } else {
    const int wb = bid - GATE_BLOCKS;            // 0..2047
    const float* src = (wb < 1024) ? w0 : w1;
    u16*        dst = (wb < 1024) ? w0_bf : w1_bf;
    const int base = (wb & 1023) * 1024 + tid * 4;
    float4 v = *(const float4*)(src + base);
    *(ushort4*)(dst + base) =
        make_ushort4(f2bf(v.x), f2bf(v.y), f2bf(v.z), f2bf(v.w));
  }
}

// ---------------------------------------------------------------------------
// Kernel 2: fused dual-GEMM, 4-phase pipeline with COUNTED vmcnt (T3+T4+T5).
// BM=256 x BN=128, BK=64, 8 waves (4M x 2N), 128 KiB LDS double-buffer.
// Per-wave load FIFO per tile: A x4 (p0), B0 x2 (p1), B1 x2 (p2).
// Waits (each immediately before an existing barrier; wait+barrier = cross-
// wave guarantee since vmcnt is per-wave):
//   p0-end:  vmcnt(4)  -> old B1[cur] landed (before p1 reads it)
//   p3-end:  vmcnt(2)  -> A+B0[next] landed; B1[next] stays IN FLIGHT
// No vmcnt(0) in the main loop (T4: drain-0 == no pipeline, m218).
// Swizzle (rule #21 both-sides): LDS dest linear, global source chunk
// permuted by (tid&7)^((tid>>4)&7); reads use chunk ((kk<<2)|fq)^(fr>>1).
// ---------------------------------------------------------------------------
__global__ __launch_bounds__(512, 2) void moe_gemm_kernel(
    const u16* __restrict__ A,    // [M,K] bf16
    const u16* __restrict__ Bw0,  // [N,K] bf16 (w0 row-major = B^T)
    const u16* __restrict__ Bw1,  // [N,K] bf16
    const float* __restrict__ bias0, const float* __restrict__ bias1,
    const float* __restrict__ scales, // [M,2]
    float* __restrict__ out)      // [M,N] f32
{
  __shared__ u16 lA [2][BM * BK];   // 64 KiB
  __shared__ u16 lB0[2][BN * BK];   // 32 KiB
  __shared__ u16 lB1[2][BN * BK];   // 32 KiB

  const int tid = threadIdx.x;

  // bijective XCD swizzle: 512 blocks, 8 XCDs, 64 blocks/XCD chunk.
  const int wgid = (blockIdx.x & 7) * 64 + (blockIdx.x >> 3);
  const int bm = wgid >> 3, bn = wgid & 7;    // bn fastest: XCD shares A panels
  const int m0 = bm * BM, n0 = bn * BN;

  const int lane = tid & 63;
  const int wid  = tid >> 6;                  // 0..7
  const int wm = wid >> 1, wn = wid & 1;      // 4M x 2N wave grid
  const int fr = lane & 15, fq = lane >> 4;
  const int frh = fr >> 1;                    // read-swizzle term

  const int schunk = ((tid & 7) ^ ((tid >> 4) & 7)) * 8;
  const u16* gA  = A   + (size_t)(m0 + (tid >> 3)) * K_TOT + schunk;
  const u16* gB0 = Bw0 + (size_t)(n0 + (tid >> 3)) * K_TOT + schunk;
  const u16* gB1 = Bw1 + (size_t)(n0 + (tid >> 3)) * K_TOT + schunk;

#define STAGE_A(buf, c, ko)  stage16(&lA [buf][(c)*4096 + tid*8], gA  + (size_t)(c)*64*K_TOT + (ko))
#define STAGE_B0(buf, c, ko) stage16(&lB0[buf][(c)*4096 + tid*8], gB0 + (size_t)(c)*64*K_TOT + (ko))
#define STAGE_B1(buf, c, ko) stage16(&lB1[buf][(c)*4096 + tid*8], gB1 + (size_t)(c)*64*K_TOT + (ko))

#define FRAG(L, buf, rowbase, kk) \
  (*(const bf16x8*)&L[buf][((rowbase) + fr) * BK + ((((kk) << 2) | fq) ^ frh) * 8])

#define BAR()        __builtin_amdgcn_s_barrier()
#define WAIT_LGKM0() do { asm volatile("s_waitcnt lgkmcnt(0)" ::: "memory"); \
                          __builtin_amdgcn_sched_barrier(0); } while (0)
#define WAIT_VM(N)   asm volatile("s_waitcnt vmcnt(" #N ")" ::: "memory")

#define MFMA16(ACC) do {                                                      \
    __builtin_amdgcn_s_setprio(1);                                            \
    _Pragma("unroll")                                                         \
    for (int i = 0; i < 4; ++i)                                               \
      _Pragma("unroll")                                                       \
      for (int j = 0; j < 4; ++j)                                             \
        ACC[i][j] = __builtin_amdgcn_mfma_f32_16x16x32_bf16(af[i], bfr[j],    \
                                                            ACC[i][j], 0,0,0);\
    __builtin_amdgcn_s_setprio(0);                                            \
  } while (0)

  f32x4 acc0[4][4] = {};
  f32x4 acc1[4][4] = {};
  bf16x8 af[4], bfr[4];

  // Prologue: stage K-tile 0 into buffer 0 (FIFO: A x4, B0 x2, B1 x2),
  // wait A+B0 (leave B1 in flight), barrier.
  STAGE_A(0, 0, 0); STAGE_A(0, 1, 0); STAGE_A(0, 2, 0); STAGE_A(0, 3, 0);
  STAGE_B0(0, 0, 0); STAGE_B0(0, 1, 0);
  STAGE_B1(0, 0, 0); STAGE_B1(0, 1, 0);
  WAIT_VM(2);
  BAR();

  int cur = 0;
  // Steady loop: tiles 0..NT-2, each prefetches tile t+1.
  for (int t = 0; t < NT - 1; ++t) {
    const int nxt = cur ^ 1;
    const size_t ko = (size_t)(t + 1) * BK;

    // ---- phase 0: expert0, kk=0 ----
    #pragma unroll
    for (int i = 0; i < 4; ++i) af[i]  = FRAG(lA,  cur, wm * 64 + i * 16, 0);
    #pragma unroll
    for (int j = 0; j < 4; ++j) bfr[j] = FRAG(lB0, cur, wn * 64 + j * 16, 0);
    STAGE_A(nxt, 0, ko); STAGE_A(nxt, 1, ko); STAGE_A(nxt, 2, ko); STAGE_A(nxt, 3, ko);
    BAR(); WAIT_LGKM0();
    MFMA16(acc0);
    WAIT_VM(4);               // old B1[cur] landed; 4 new A stay in flight
    BAR();

    // ---- phase 1: expert1, kk=0 (A frags reused) ----
    #pragma unroll
    for (int j = 0; j < 4; ++j) bfr[j] = FRAG(lB1, cur, wn * 64 + j * 16, 0);
    STAGE_B0(nxt, 0, ko); STAGE_B0(nxt, 1, ko);
    BAR(); WAIT_LGKM0();
    MFMA16(acc1);
    BAR();

    // ---- phase 2: expert0, kk=1 ----
    #pragma unroll
    for (int i = 0; i < 4; ++i) af[i]  = FRAG(lA,  cur, wm * 64 + i * 16, 1);
    #pragma unroll
    for (int j = 0; j < 4; ++j) bfr[j] = FRAG(lB0, cur, wn * 64 + j * 16, 1);
    STAGE_B1(nxt, 0, ko); STAGE_B1(nxt, 1, ko);
    BAR(); WAIT_LGKM0();
    MFMA16(acc0);
    BAR();

    // ---- phase 3: expert1, kk=1 ----
    #pragma unroll
    for (int j = 0; j < 4; ++j) bfr[j] = FRAG(lB1, cur, wn * 64 + j * 16, 1);
    BAR(); WAIT_LGKM0();
    MFMA16(acc1);
    WAIT_VM(2);               // A+B0[next] landed; B1[next] stays in flight
    BAR();
    cur = nxt;
  }

  // Peeled last tile (no prefetch): only extra wait is B1 drain at p0-end.
  {
    #pragma unroll
    for (int i = 0; i < 4; ++i) af[i]  = FRAG(lA,  cur, wm * 64 + i * 16, 0);
    #pragma unroll
    for (int j = 0; j < 4; ++j) bfr[j] = FRAG(lB0, cur, wn * 64 + j * 16, 0);
    BAR(); WAIT_LGKM0();
    MFMA16(acc0);
    WAIT_VM(0);
    BAR();

    #pragma unroll
    for (int j = 0; j < 4; ++j) bfr[j] = FRAG(lB1, cur, wn * 64 + j * 16, 0);
    BAR(); WAIT_LGKM0();
    MFMA16(acc1);
    BAR();

    #pragma unroll
    for (int i = 0; i < 4; ++i) af[i]  = FRAG(lA,  cur, wm * 64 + i * 16, 1);
    #pragma unroll
    for (int j = 0; j < 4; ++j) bfr[j] = FRAG(lB0, cur, wn * 64 + j * 16, 1);
    BAR(); WAIT_LGKM0();
    MFMA16(acc0);
    BAR();

    #pragma unroll
    for (int j = 0; j < 4; ++j) bfr[j] = FRAG(lB1, cur, wn * 64 + j * 16, 1);
    BAR(); WAIT_LGKM0();
    MFMA16(acc1);
  }

  // Epilogue: out = s0*silu(acc0+b0) + s1*silu(acc1+b1)
  float bb0[4], bb1[4];
  #pragma unroll
  for (int j = 0; j < 4; ++j) {
    const int col = n0 + wn * 64 + j * 16 + fr;
    bb0[j] = bias0[col];
    bb1[j] = bias1[col];
  }
  #pragma unroll
  for (int i = 0; i < 4; ++i) {
    #pragma unroll
    for (int r = 0; r < 4; ++r) {
      const int grow = m0 + wm * 64 + i * 16 + fq * 4 + r;  // C row=(lane>>4)*4+reg
      const float s0 = scales[grow * 2 + 0];
      const float s1 = scales[grow * 2 + 1];
      float* orow = out + (size_t)grow * N_TOT + n0 + wn * 64;
      #pragma unroll
      for (int j = 0; j < 4; ++j) {
        const float v0 = acc0[i][j][r] + bb0[j];
        const float v1 = acc1[i][j][r] + bb1[j];
        const float g0 = v0 / (1.0f + __expf(-v0));
        const float g1 = v1 / (1.0f + __expf(-v1));
        orow[j * 16 + fr] = s0 * g0 + s1 * g1;              // col = lane&15
      }
    }
  }
#undef STAGE_A
#undef STAGE_B0
#undef STAGE_B1
#undef FRAG
#undef BAR
#undef WAIT_LGKM0
#undef WAIT_VM
#undef MFMA16
}

// ---------------------------------------------------------------------------
extern "C" void kernel_launch(void* const* d_in, const int* in_sizes, int n_in,
                              void* d_out, int out_size, void* d_ws, size_t ws_size,
                              hipStream_t stream)
{
  const float* tokens = (const float*)d_in[0];
  const float* gate_w = (const float*)d_in[1];
  const float* w0     = (const float*)d_in[2];
  const float* b0     = (const float*)d_in[3];
  const float* w1     = (const float*)d_in[4];
  const float* b1     = (const float*)d_in[5];
  float* out = (float*)d_out;

  char* ws = (char*)d_ws;
  u16* tok_bf = (u16*)ws;                                               // 32 MB
  u16* w0_bf  = (u16*)(ws + (size_t)M_TOT * K_TOT * 2);                 //  2 MB
  u16* w1_bf  = (u16*)(ws + (size_t)M_TOT * K_TOT * 2 + (size_t)N_TOT * K_TOT * 2);
  float* scales = (float*)(ws + (size_t)M_TOT * K_TOT * 2 + (size_t)2 * N_TOT * K_TOT * 2);

  gate_convert_kernel<<<GATE_BLOCKS + 2048, 256, 0, stream>>>(
      tokens, gate_w, w0, w1, tok_bf, w0_bf, w1_bf, scales);

  moe_gemm_kernel<<<(M_TOT/BM) * (N_TOT/BN), 512, 0, stream>>>(
      tok_bf, w0_bf, w1_bf, b0, b1, scales, out);
}

// Round 8
// 101.317 us; speedup vs baseline: 1.0393x; 1.0393x over previous
//
#include <hip/hip_runtime.h>
#include <hip/hip_bf16.h>

typedef unsigned short u16;
typedef __bf16 bf16x8 __attribute__((ext_vector_type(8)));
typedef float  f32x4  __attribute__((ext_vector_type(4)));

#define BB    4
#define SS    4096
#define DD    1024
#define EE    8
#define M_TOT (BB*SS)   /* 16384 */
#define N_TOT DD        /* 1024  */
#define K_TOT DD        /* 1024  */

#define BM 256
#define BN 128
#define BK 64
#define NT (K_TOT/BK)   /* 16 K-tiles */

#define GATE_BLOCKS 1024   /* 16 tokens per block, 4 per wave */

__device__ __forceinline__ u16 f2bf(float f) {
  unsigned u = __builtin_bit_cast(unsigned, f);
  u += 0x7fffu + ((u >> 16) & 1u);          // round-to-nearest-even
  return (u16)(u >> 16);
}

__device__ __forceinline__ void stage16(u16* lds, const u16* g) {
  __builtin_amdgcn_global_load_lds((const __attribute__((address_space(1))) void*)g,
                                   (__attribute__((address_space(3))) void*)lds,
                                   16, 0, 0);
}

// ---------------------------------------------------------------------------
// Kernel 1: gate (fp32, exact) + token f32->bf16 convert, plus weight convert.
// (unchanged — measured ~92% of achievable HBM BW)
// ---------------------------------------------------------------------------
__global__ __launch_bounds__(256) void gate_convert_kernel(
    const float* __restrict__ tokens, const float* __restrict__ gate_w,
    const float* __restrict__ w0,     const float* __restrict__ w1,
    u16* __restrict__ tok_bf, u16* __restrict__ w0_bf, u16* __restrict__ w1_bf,
    float* __restrict__ scales)
{
  const int bid = blockIdx.x;
  const int tid = threadIdx.x;

  if (bid < GATE_BLOCKS) {
    __shared__ float gwT[EE][DD];       // 32 KB, transposed gate weights
    #pragma unroll
    for (int r = 0; r < 4; ++r) {
      const int d = r * 256 + tid;      // coalesced: lanes 32B apart
      float4 a = *(const float4*)&gate_w[d * EE];
      float4 b = *(const float4*)&gate_w[d * EE + 4];
      gwT[0][d] = a.x; gwT[1][d] = a.y; gwT[2][d] = a.z; gwT[3][d] = a.w;
      gwT[4][d] = b.x; gwT[5][d] = b.y; gwT[6][d] = b.z; gwT[7][d] = b.w;
    }
    __syncthreads();

    const int lane = tid & 63, wid = tid >> 6;
    const int tbase = (bid * 4 + wid) * 4;          // 4 tokens per wave

    float lg[4][EE];
    #pragma unroll
    for (int t = 0; t < 4; ++t)
      #pragma unroll
      for (int e = 0; e < EE; ++e) lg[t][e] = 0.0f;

    #pragma unroll
    for (int c = 0; c < 4; ++c) {
      const int d = c * 256 + lane * 4;
      float4 gw[EE];
      #pragma unroll
      for (int e = 0; e < EE; ++e)
        gw[e] = *(const float4*)&gwT[e][d];         // ds_read_b128, lanes 16B apart
      #pragma unroll
      for (int t = 0; t < 4; ++t) {
        const size_t off = (size_t)(tbase + t) * DD + d;
        float4 v = *(const float4*)(tokens + off);
        *(ushort4*)(tok_bf + off) =
            make_ushort4(f2bf(v.x), f2bf(v.y), f2bf(v.z), f2bf(v.w));
        #pragma unroll
        for (int e = 0; e < EE; ++e)
          lg[t][e] = fmaf(v.w, gw[e].w, fmaf(v.z, gw[e].z,
                     fmaf(v.y, gw[e].y, fmaf(v.x, gw[e].x, lg[t][e]))));
      }
    }

    // Expert-splitting butterfly reduce, then shuffle softmax/top-2.
    const int b0 = lane & 1, b1 = (lane >> 1) & 1, b2 = (lane >> 2) & 1;
    const int E  = b0 * 4 + (lane & 2) + b2;

    #pragma unroll
    for (int t = 0; t < 4; ++t) {
      float n0[4], n1[2], rr;
      #pragma unroll
      for (int i = 0; i < 4; ++i) {
        float send = b0 ? lg[t][i] : lg[t][i + 4];
        float keep = b0 ? lg[t][i + 4] : lg[t][i];
        n0[i] = keep + __shfl_xor(send, 1, 64);
      }
      #pragma unroll
      for (int i = 0; i < 2; ++i) {
        float send = b1 ? n0[i] : n0[i + 2];
        float keep = b1 ? n0[i + 2] : n0[i];
        n1[i] = keep + __shfl_xor(send, 2, 64);
      }
      {
        float send = b2 ? n1[0] : n1[1];
        float keep = b2 ? n1[1] : n1[0];
        rr = keep + __shfl_xor(send, 4, 64);
      }
      rr += __shfl_xor(rr, 8, 64);
      rr += __shfl_xor(rr, 16, 64);
      rr += __shfl_xor(rr, 32, 64);

      float m = rr;
      m = fmaxf(m, __shfl_xor(m, 1, 64));
      m = fmaxf(m, __shfl_xor(m, 2, 64));
      m = fmaxf(m, __shfl_xor(m, 4, 64));
      float p = __expf(rr - m);
      float s = p;
      s += __shfl_xor(s, 1, 64);
      s += __shfl_xor(s, 2, 64);
      s += __shfl_xor(s, 4, 64);

      int cnt = 0;
      #pragma unroll
      for (int k = 1; k < 8; ++k) {
        float Lo = __shfl_xor(rr, k, 64);
        const int Eo = E ^ ((k & 1) * 4 + (k & 2) + ((k >> 2) & 1));
        cnt += (Lo > rr || (Lo == rr && Eo < E)) ? 1 : 0;
      }
      if (lane < 8) {
        const float w = p / s;
        if (E == 0) scales[(tbase + t) * 2 + 0] = (cnt == 0) ? w : 0.0f;
        if (E == 1) scales[(tbase + t) * 2 + 1] = (cnt == 1) ? w : 0.0f;
      }
    }
  } else {
    const int wb = bid - GATE_BLOCKS;            // 0..2047
    const float* src = (wb < 1024) ? w0 : w1;
    u16*        dst = (wb < 1024) ? w0_bf : w1_bf;
    const int base = (wb & 1023) * 1024 + tid * 4;
    float4 v = *(const float4*)(src + base);
    *(ushort4*)(dst + base) =
        make_ushort4(f2bf(v.x), f2bf(v.y), f2bf(v.z), f2bf(v.w));
  }
}

// ---------------------------------------------------------------------------
// Kernel 2: fused dual-GEMM, v3: compiler-scheduled fragment prefetch.
// BM=256 x BN=128, BK=64, 8 waves (4M x 2N), 128 KiB LDS double-buffer.
//
// Round-7 lesson: manual lgkmcnt(0)+sched_barrier per phase serializes
// LDS-reads against MFMA (convoy: reads 1.7K cyc + MFMA 2.5K cyc additive
// = measured 6.2K cyc/tile, MfmaUtil 33%).  v3: NO manual lgkm — all frag
// reads are plain loads issued a phase early; the compiler emits counted
// lgkmcnt (m97 evidence) so the LDS pipe fills DURING MFMA.
// Only 2 barriers/tile (the two real cross-wave staging syncs):
//   p0-end: vmcnt(4)+BAR  -> old B1[cur] landed before b1 reads
//   t-end:  vmcnt(2)+BAR  -> A'+B0' landed; B1' stays IN FLIGHT
// Swizzle (rule #21 both-sides) unchanged: dest linear, source chunk
// (tid&7)^((tid>>4)&7), reads chunk ((kk<<2)|fq)^(fr>>1).
// ---------------------------------------------------------------------------
__global__ __launch_bounds__(512, 2) void moe_gemm_kernel(
    const u16* __restrict__ A,    // [M,K] bf16
    const u16* __restrict__ Bw0,  // [N,K] bf16 (w0 row-major = B^T)
    const u16* __restrict__ Bw1,  // [N,K] bf16
    const float* __restrict__ bias0, const float* __restrict__ bias1,
    const float* __restrict__ scales, // [M,2]
    float* __restrict__ out)      // [M,N] f32
{
  __shared__ u16 lA [2][BM * BK];   // 64 KiB
  __shared__ u16 lB0[2][BN * BK];   // 32 KiB
  __shared__ u16 lB1[2][BN * BK];   // 32 KiB

  const int tid = threadIdx.x;

  // bijective XCD swizzle: 512 blocks, 8 XCDs, 64 blocks/XCD chunk.
  const int wgid = (blockIdx.x & 7) * 64 + (blockIdx.x >> 3);
  const int bm = wgid >> 3, bn = wgid & 7;    // bn fastest: XCD shares A panels
  const int m0 = bm * BM, n0 = bn * BN;

  const int lane = tid & 63;
  const int wid  = tid >> 6;                  // 0..7
  const int wm = wid >> 1, wn = wid & 1;      // 4M x 2N wave grid
  const int fr = lane & 15, fq = lane >> 4;
  const int frh = fr >> 1;                    // read-swizzle term

  const int schunk = ((tid & 7) ^ ((tid >> 4) & 7)) * 8;
  const u16* gA  = A   + (size_t)(m0 + (tid >> 3)) * K_TOT + schunk;
  const u16* gB0 = Bw0 + (size_t)(n0 + (tid >> 3)) * K_TOT + schunk;
  const u16* gB1 = Bw1 + (size_t)(n0 + (tid >> 3)) * K_TOT + schunk;

#define STAGE_A(buf, c, ko)  stage16(&lA [buf][(c)*4096 + tid*8], gA  + (size_t)(c)*64*K_TOT + (ko))
#define STAGE_B0(buf, c, ko) stage16(&lB0[buf][(c)*4096 + tid*8], gB0 + (size_t)(c)*64*K_TOT + (ko))
#define STAGE_B1(buf, c, ko) stage16(&lB1[buf][(c)*4096 + tid*8], gB1 + (size_t)(c)*64*K_TOT + (ko))

#define FRAG(L, buf, rowbase, kk) \
  (*(const bf16x8*)&L[buf][((rowbase) + fr) * BK + ((((kk) << 2) | fq) ^ frh) * 8])

#define BAR()        __builtin_amdgcn_s_barrier()
#define WAIT_VM(N)   asm volatile("s_waitcnt vmcnt(" #N ")" ::: "memory")

#define MFMA16(ACC, AF, BF) do {                                              \
    __builtin_amdgcn_s_setprio(1);                                            \
    _Pragma("unroll")                                                         \
    for (int i = 0; i < 4; ++i)                                               \
      _Pragma("unroll")                                                       \
      for (int j = 0; j < 4; ++j)                                             \
        ACC[i][j] = __builtin_amdgcn_mfma_f32_16x16x32_bf16(AF[i], BF[j],     \
                                                            ACC[i][j], 0,0,0);\
    __builtin_amdgcn_s_setprio(0);                                            \
  } while (0)

  f32x4 acc0[4][4] = {};
  f32x4 acc1[4][4] = {};
  bf16x8 af0[4], af1[4], bA[4], bB[4];   // named frag banks (rule 20)

  // Prologue: stage K-tile 0 (FIFO: A x4, B0 x2, B1 x2); wait A+B0, leave
  // B1 in flight (steady-state invariant); barrier.
  STAGE_A(0, 0, 0); STAGE_A(0, 1, 0); STAGE_A(0, 2, 0); STAGE_A(0, 3, 0);
  STAGE_B0(0, 0, 0); STAGE_B0(0, 1, 0);
  STAGE_B1(0, 0, 0); STAGE_B1(0, 1, 0);
  WAIT_VM(2);
  BAR();

  int cur = 0;
  // Steady tiles 0..NT-2 (each prefetches tile t+1).
  for (int t = 0; t < NT - 1; ++t) {
    const int nxt = cur ^ 1;
    const size_t ko = (size_t)(t + 1) * BK;

    // ---- p0: issue ALL k0+k1 A/B0 reads; stage A'; MFMA e0k0 ----
    #pragma unroll
    for (int i = 0; i < 4; ++i) af0[i] = FRAG(lA,  cur, wm * 64 + i * 16, 0);
    #pragma unroll
    for (int j = 0; j < 4; ++j) bA[j]  = FRAG(lB0, cur, wn * 64 + j * 16, 0);
    #pragma unroll
    for (int i = 0; i < 4; ++i) af1[i] = FRAG(lA,  cur, wm * 64 + i * 16, 1);
    #pragma unroll
    for (int j = 0; j < 4; ++j) bB[j]  = FRAG(lB0, cur, wn * 64 + j * 16, 1);
    STAGE_A(nxt, 0, ko); STAGE_A(nxt, 1, ko); STAGE_A(nxt, 2, ko); STAGE_A(nxt, 3, ko);
    MFMA16(acc0, af0, bA);          // compiler waits lgkm for first 8 only
    WAIT_VM(4);                     // old B1[cur] landed; 4 new A in flight
    BAR();

    // ---- barrier-free region: e0k1, e1k0, e1k1 with overlapped b1 reads ----
    #pragma unroll
    for (int j = 0; j < 4; ++j) bA[j] = FRAG(lB1, cur, wn * 64 + j * 16, 0);
    STAGE_B0(nxt, 0, ko); STAGE_B0(nxt, 1, ko);
    MFMA16(acc0, af1, bB);          // b1k0 reads overlap this batch

    #pragma unroll
    for (int j = 0; j < 4; ++j) bB[j] = FRAG(lB1, cur, wn * 64 + j * 16, 1);
    STAGE_B1(nxt, 0, ko);  STAGE_B1(nxt, 1, ko);
    MFMA16(acc1, af0, bA);          // b1k1 reads overlap this batch

    MFMA16(acc1, af1, bB);

    WAIT_VM(2);                     // A'+B0' landed; B1' stays in flight
    BAR();
    cur = nxt;
  }

  // Peeled last tile (no prefetch): must fully drain B1 before b1 reads.
  {
    #pragma unroll
    for (int i = 0; i < 4; ++i) af0[i] = FRAG(lA,  cur, wm * 64 + i * 16, 0);
    #pragma unroll
    for (int j = 0; j < 4; ++j) bA[j]  = FRAG(lB0, cur, wn * 64 + j * 16, 0);
    #pragma unroll
    for (int i = 0; i < 4; ++i) af1[i] = FRAG(lA,  cur, wm * 64 + i * 16, 1);
    #pragma unroll
    for (int j = 0; j < 4; ++j) bB[j]  = FRAG(lB0, cur, wn * 64 + j * 16, 1);
    MFMA16(acc0, af0, bA);
    WAIT_VM(0);
    BAR();

    #pragma unroll
    for (int j = 0; j < 4; ++j) bA[j] = FRAG(lB1, cur, wn * 64 + j * 16, 0);
    MFMA16(acc0, af1, bB);

    #pragma unroll
    for (int j = 0; j < 4; ++j) bB[j] = FRAG(lB1, cur, wn * 64 + j * 16, 1);
    MFMA16(acc1, af0, bA);
    MFMA16(acc1, af1, bB);
  }

  // Epilogue: out = s0*silu(acc0+b0) + s1*silu(acc1+b1)
  float bb0[4], bb1[4];
  #pragma unroll
  for (int j = 0; j < 4; ++j) {
    const int col = n0 + wn * 64 + j * 16 + fr;
    bb0[j] = bias0[col];
    bb1[j] = bias1[col];
  }
  #pragma unroll
  for (int i = 0; i < 4; ++i) {
    #pragma unroll
    for (int r = 0; r < 4; ++r) {
      const int grow = m0 + wm * 64 + i * 16 + fq * 4 + r;  // C row=(lane>>4)*4+reg
      const float s0 = scales[grow * 2 + 0];
      const float s1 = scales[grow * 2 + 1];
      float* orow = out + (size_t)grow * N_TOT + n0 + wn * 64;
      #pragma unroll
      for (int j = 0; j < 4; ++j) {
        const float v0 = acc0[i][j][r] + bb0[j];
        const float v1 = acc1[i][j][r] + bb1[j];
        const float g0 = v0 / (1.0f + __expf(-v0));
        const float g1 = v1 / (1.0f + __expf(-v1));
        orow[j * 16 + fr] = s0 * g0 + s1 * g1;              // col = lane&15
      }
    }
  }
#undef STAGE_A
#undef STAGE_B0
#undef STAGE_B1
#undef FRAG
#undef BAR
#undef WAIT_VM
#undef MFMA16
}

// ---------------------------------------------------------------------------
extern "C" void kernel_launch(void* const* d_in, const int* in_sizes, int n_in,
                              void* d_out, int out_size, void* d_ws, size_t ws_size,
                              hipStream_t stream)
{
  const float* tokens = (const float*)d_in[0];
  const float* gate_w = (const float*)d_in[1];
  const float* w0     = (const float*)d_in[2];
  const float* b0     = (const float*)d_in[3];
  const float* w1     = (const float*)d_in[4];
  const float* b1     = (const float*)d_in[5];
  float* out = (float*)d_out;

  char* ws = (char*)d_ws;
  u16* tok_bf = (u16*)ws;                                               // 32 MB
  u16* w0_bf  = (u16*)(ws + (size_t)M_TOT * K_TOT * 2);                 //  2 MB
  u16* w1_bf  = (u16*)(ws + (size_t)M_TOT * K_TOT * 2 + (size_t)N_TOT * K_TOT * 2);
  float* scales = (float*)(ws + (size_t)M_TOT * K_TOT * 2 + (size_t)2 * N_TOT * K_TOT * 2);

  gate_convert_kernel<<<GATE_BLOCKS + 2048, 256, 0, stream>>>(
      tokens, gate_w, w0, w1, tok_bf, w0_bf, w1_bf, scales);

  moe_gemm_kernel<<<(M_TOT/BM) * (N_TOT/BN), 512, 0, stream>>>(
      tok_bf, w0_bf, w1_bf, b0, b1, scales, out);
}